// Round 1
// baseline (1131.735 us; speedup 1.0000x reference)
//
#include <hip/hip_runtime.h>
#include <math.h>

#define HOP 441
#define NMEL 80

__device__ __forceinline__ float2 cmulf(float2 a, float2 b) {
    return make_float2(a.x * b.x - a.y * b.y, a.x * b.y + a.y * b.x);
}

// One workgroup = FPB consecutive frames of one batch row, one FFT size.
// Phases: twiddle table -> per-frame {load+window+pack, Stockham FFT (gather,
// ping-pong LDS), rfft unpack -> power -> bf16 LDS [k][frame]} -> mel matmul
// (vector fp32, mel read once per WG) -> log -> strided store (stride 3 = size idx).
template<int FLEN, int FPB, int SZI>
__global__ __launch_bounds__(512)
void spect_kernel(const float* __restrict__ x, const float* __restrict__ win,
                  const float* __restrict__ mel, float* __restrict__ out,
                  int T, int n0) {
    constexpr int N    = FLEN / 2;                 // complex FFT size
    constexpr int LOGN = (FLEN == 1024) ? 9 : ((FLEN == 2048) ? 10 : 11);
    constexpr int K    = N + 1;                    // rfft bins
    constexpr int KP   = N + 8;                    // padded rows for pow store
    constexpr int HALF = FLEN / 2;
    constexpr int NT   = 512;

    __shared__ union ShU {
        struct { float2 A[N]; float2 B[N]; } f;    // FFT ping-pong
        float res[FPB * NMEL];                     // mel results (reused after FFTs)
    } sh;
    __shared__ float2 tw[N / 2];
    __shared__ uint4 pows4[(KP * FPB) / 8];        // bf16 power, layout [k][frame]
    unsigned short* pows = (unsigned short*)pows4;

    const int tid = threadIdx.x;
    const int b   = blockIdx.y;
    const int t0  = blockIdx.x * FPB;

    // twiddle table: tw[q] = exp(-2*pi*i*q/N), q in [0, N/2)
    for (int i = tid; i < N / 2; i += NT) {
        float s, c;
        sincosf(-6.283185307179586f * (float)i / (float)N, &s, &c);
        tw[i] = make_float2(c, s);
    }
    __syncthreads();

    const float* xb = x + (size_t)b * (size_t)T;
    const int Tp = T + HALF;

    for (int fi = 0; fi < FPB; ++fi) {
        const int t = t0 + fi;
        if (t >= n0) {   // uniform branch; zero this pow column so mel is clean
            for (int k = tid; k < K; k += NT) pows[k * FPB + fi] = 0;
            continue;
        }
        const int start = HOP * t;
        int pad = start + FLEN - Tp; if (pad < 0) pad = 0;   // tail front-zero count
        const int base = start - pad - HALF;                 // x index of frame pos j

        // load + window + pack pairs into complex z[j] = fr[2j] + i*fr[2j+1]
        for (int i = tid; i < N; i += NT) {
            const int j0 = 2 * i;
            const float2 w2 = ((const float2*)win)[i];
            const int xi0 = base + j0;
            const int xi1 = xi0 + 1;
            float s0 = (j0 >= pad     && xi0 >= 0) ? xb[xi0] * w2.x : 0.0f;
            float s1 = (j0 + 1 >= pad && xi1 >= 0) ? xb[xi1] * w2.y : 0.0f;
            sh.f.A[i] = make_float2(s0, s1);
        }
        __syncthreads();

        // Stockham radix-2, gather form: contiguous writes, broadcast-friendly reads
        float2* src = sh.f.A;
        float2* dst = sh.f.B;
        for (int s = 0; s < LOGN; ++s) {
            const int m = 1 << s;
            for (int u = tid; u < N; u += NT) {
                const int j  = u & (m - 1);
                const int r  = u >> s;
                const int k2 = r >> 1;
                const int ti = (k2 << s) + j;
                const float2 a  = src[ti];
                const float2 bb = src[ti + N / 2];
                float2 v;
                if (r & 1) {
                    const float2 d = make_float2(a.x - bb.x, a.y - bb.y);
                    v = cmulf(d, tw[k2 << s]);
                } else {
                    v = make_float2(a.x + bb.x, a.y + bb.y);
                }
                dst[u] = v;
            }
            __syncthreads();
            float2* tmp = src; src = dst; dst = tmp;
        }

        // unpack rfft from half-size complex FFT, power, store bf16 (truncated)
        for (int k = tid; k < K; k += NT) {
            const float2 Zk = src[k & (N - 1)];          // k==N wraps to Z[0]
            const float2 Zn = src[(N - k) & (N - 1)];
            const float Er = 0.5f * (Zk.x + Zn.x);
            const float Ei = 0.5f * (Zk.y - Zn.y);
            const float Dr = Zk.x - Zn.x;
            const float Di = Zk.y + Zn.y;
            const float Or = 0.5f * Di;                  // O = -i/2 * (Zk - conj(Zn))
            const float Oi = -0.5f * Dr;
            float sw, cw;
            __sincosf(3.14159265358979f * (float)k / (float)N, &sw, &cw);  // W = (cw, -sw)
            const float Xr = Er + cw * Or + sw * Oi;
            const float Xi = Ei + cw * Oi - sw * Or;
            const float p = Xr * Xr + Xi * Xi;
            pows[k * FPB + fi] = (unsigned short)(__float_as_uint(p) >> 16);
        }
        __syncthreads();
    }

    // ---- mel: out[fi][m] = sum_k pow[k][fi] * mel[k][m] ----
    float* res = sh.res;
    for (int i = tid; i < FPB * NMEL; i += NT) res[i] = 0.0f;
    __syncthreads();

    constexpr int NCH = 25;                    // k-chunks
    constexpr int CH  = (K + NCH - 1) / NCH;
    if (tid < NCH * 20) {
        const int g  = tid % 20;               // m-group: mel bins 4g..4g+3
        const int c  = tid / 20;               // k-chunk
        const int k0 = c * CH;
        const int k1 = (k0 + CH < K) ? (k0 + CH) : K;
        float acc[FPB][4];
        #pragma unroll
        for (int f2 = 0; f2 < FPB; ++f2) {
            acc[f2][0] = 0.f; acc[f2][1] = 0.f; acc[f2][2] = 0.f; acc[f2][3] = 0.f;
        }
        for (int k = k0; k < k1; ++k) {
            const float4 mr = *(const float4*)(mel + (size_t)k * NMEL + 4 * g);
            const uint4* prow = (const uint4*)(pows + k * FPB);
#define ACC2(W32, BASE) { \
            const float p0 = __uint_as_float((W32) << 16); \
            const float p1 = __uint_as_float((W32) & 0xFFFF0000u); \
            acc[BASE][0] += p0 * mr.x; acc[BASE][1] += p0 * mr.y; \
            acc[BASE][2] += p0 * mr.z; acc[BASE][3] += p0 * mr.w; \
            acc[(BASE)+1][0] += p1 * mr.x; acc[(BASE)+1][1] += p1 * mr.y; \
            acc[(BASE)+1][2] += p1 * mr.z; acc[(BASE)+1][3] += p1 * mr.w; }
            {
                const uint4 pv = prow[0];
                ACC2(pv.x, 0) ACC2(pv.y, 2) ACC2(pv.z, 4) ACC2(pv.w, 6)
            }
            if constexpr (FPB == 16) {
                const uint4 pv = prow[1];
                ACC2(pv.x, 8) ACC2(pv.y, 10) ACC2(pv.z, 12) ACC2(pv.w, 14)
            }
#undef ACC2
        }
        #pragma unroll
        for (int f2 = 0; f2 < FPB; ++f2) {
            #pragma unroll
            for (int mi = 0; mi < 4; ++mi) {
                atomicAdd(&res[f2 * NMEL + 4 * g + mi], acc[f2][mi]);
            }
        }
    }
    __syncthreads();

    const size_t outbase = (size_t)b * (size_t)n0 * NMEL * 3;
    for (int i = tid; i < FPB * NMEL; i += NT) {
        const int f2 = i / NMEL;
        const int m  = i % NMEL;
        const int t  = t0 + f2;
        if (t < n0) {
            out[outbase + ((size_t)t * NMEL + m) * 3 + SZI] = logf(res[i] + 1e-16f);
        }
    }
}

extern "C" void kernel_launch(void* const* d_in, const int* in_sizes, int n_in,
                              void* d_out, int out_size, void* d_ws, size_t ws_size,
                              hipStream_t stream) {
    const float* x  = (const float*)d_in[0];
    const float* w1 = (const float*)d_in[1];
    const float* m1 = (const float*)d_in[2];
    const float* w2 = (const float*)d_in[3];
    const float* m2 = (const float*)d_in[4];
    const float* w4 = (const float*)d_in[5];
    const float* m4 = (const float*)d_in[6];
    float* out = (float*)d_out;

    const int B  = 8;
    const int T  = in_sizes[0] / B;
    const int n0 = (T + 512 + 440) / 441;   // ceil((T + 1024/2) / 441)

    spect_kernel<1024, 16, 0><<<dim3((n0 + 15) / 16, B), 512, 0, stream>>>(x, w1, m1, out, T, n0);
    spect_kernel<2048, 16, 1><<<dim3((n0 + 15) / 16, B), 512, 0, stream>>>(x, w2, m2, out, T, n0);
    spect_kernel<4096,  8, 2><<<dim3((n0 +  7) /  8, B), 512, 0, stream>>>(x, w4, m4, out, T, n0);
}

// Round 2
// 869.155 us; speedup vs baseline: 1.3021x; 1.3021x over previous
//
#include <hip/hip_runtime.h>
#include <math.h>

#define HOP 441
#define NMEL 80

__device__ __forceinline__ float2 cmulf(float2 a, float2 b) {
    return make_float2(a.x * b.x - a.y * b.y, a.x * b.y + a.y * b.x);
}
__device__ __forceinline__ float2 cadd(float2 a, float2 b) {
    return make_float2(a.x + b.x, a.y + b.y);
}
__device__ __forceinline__ float2 csub(float2 a, float2 b) {
    return make_float2(a.x - b.x, a.y - b.y);
}

// One workgroup = FPB consecutive frames of one batch row, one FFT size.
// FFT: radix-4 gather Stockham (DIF), one butterfly per thread, CONC frames
// processed concurrently by sub-groups of TPF = N/4 threads. Power spectra
// staged bf16 in LDS [k][frame]; mel matrix read once per WG.
template<int FLEN, int FPB, int SZI>
__global__ __launch_bounds__(512)
void spect_kernel(const float* __restrict__ x, const float* __restrict__ win,
                  const float* __restrict__ mel, float* __restrict__ out,
                  int T, int n0) {
    constexpr int N     = FLEN / 2;                 // complex FFT size
    constexpr int LOGN  = (FLEN == 1024) ? 9 : ((FLEN == 2048) ? 10 : 11);
    constexpr int NR4   = LOGN / 2;                 // radix-4 stages
    constexpr bool HASR2 = (LOGN & 1) != 0;         // trailing radix-2 stage
    constexpr int K     = N + 1;                    // rfft bins
    constexpr int KP    = N + 8;                    // padded rows for pow store
    constexpr int HALF  = FLEN / 2;
    constexpr int NT    = 512;
    constexpr int TPF   = N / 4;                    // threads per frame (butterflies/stage)
    constexpr int CONC  = NT / TPF;                 // frames in flight per group

    __shared__ union ShU {
        float2 buf[2][CONC][N];                     // FFT ping-pong (32 KB total)
        float res[FPB * NMEL];                      // mel results (reused after FFTs)
    } sh;
    __shared__ float2 tw[N / 2];
    __shared__ uint4 pows4[(KP * FPB) / 8];         // bf16 power, layout [k][frame]
    unsigned short* pows = (unsigned short*)pows4;

    const int tid   = threadIdx.x;
    const int sub   = tid / TPF;                    // which concurrent frame
    const int ulane = tid & (TPF - 1);              // lane within frame group
    const int b     = blockIdx.y;
    const int t0    = blockIdx.x * FPB;

    // twiddle table: tw[q] = exp(-2*pi*i*q/N), q in [0, N/2)
    for (int i = tid; i < N / 2; i += NT) {
        float s, c;
        sincosf(-6.283185307179586f * (float)i / (float)N, &s, &c);
        tw[i] = make_float2(c, s);
    }

    const float* xb = x + (size_t)b * (size_t)T;
    const int Tp = T + HALF;

    for (int fi = 0; fi < FPB; fi += CONC) {
        __syncthreads();   // previous group's unpack reads done (also covers tw fill)

        const int t = t0 + fi + sub;
        const bool valid = (t < n0);
        const int start = HOP * t;
        int pad = start + FLEN - Tp; if (pad < 0) pad = 0;   // tail front-zero count
        const int base = start - pad - HALF;                 // x index of frame pos j

        // load + window + pack pairs into complex z[i] = fr[2i] + i*fr[2i+1]
        {
            float2* A0 = sh.buf[0][sub];
            #pragma unroll
            for (int it = 0; it < N / TPF; ++it) {
                const int i  = ulane + it * TPF;
                const int j0 = 2 * i;
                const float2 w2 = ((const float2*)win)[i];
                const int xi0 = base + j0;
                const int xi1 = xi0 + 1;
                float s0 = (valid && j0 >= pad     && xi0 >= 0) ? xb[xi0] * w2.x : 0.0f;
                float s1 = (valid && j0 + 1 >= pad && xi1 >= 0) ? xb[xi1] * w2.y : 0.0f;
                A0[i] = make_float2(s0, s1);
            }
        }
        __syncthreads();

        // radix-4 Stockham stages: read at fixed strides, sorted output
        int cur = 0;
        #pragma unroll
        for (int p = 0; p < NR4; ++p) {
            const int m = 1 << (2 * p);
            const float2* src = sh.buf[cur][sub];
            float2*       dst = sh.buf[cur ^ 1][sub];
            const int u = ulane;
            const float2 A = src[u];
            const float2 C = src[u + N / 4];
            const float2 B = src[u + N / 2];
            const float2 D = src[u + 3 * N / 4];
            const int tb = u & ~(m - 1);            // m*k2
            const float2 w1  = tw[tb];
            const float2 w2t = tw[2 * tb];
            const float2 w3  = cmulf(w1, w2t);
            const float2 P = cadd(A, B), Q = csub(A, B);
            const float2 R = cadd(C, D), S = csub(C, D);
            const float2 QmiS = make_float2(Q.x + S.y, Q.y - S.x);   // Q - i*S
            const float2 QpiS = make_float2(Q.x - S.y, Q.y + S.x);   // Q + i*S
            const float2 o0 = cadd(P, R);
            const float2 o1 = cmulf(QmiS, w1);
            const float2 o2 = cmulf(csub(P, R), w2t);
            const float2 o3 = cmulf(QpiS, w3);
            const int dbase = (u & (m - 1)) + ((u >> (2 * p)) << (2 * p + 2));
            dst[dbase]         = o0;
            dst[dbase + m]     = o1;
            dst[dbase + 2 * m] = o2;
            dst[dbase + 3 * m] = o3;
            cur ^= 1;
            __syncthreads();
        }
        if constexpr (HASR2) {                      // final radix-2, twiddle-free (DIF)
            const float2* src = sh.buf[cur][sub];
            float2*       dst = sh.buf[cur ^ 1][sub];
            #pragma unroll
            for (int q = 0; q < 2; ++q) {
                const int j = ulane + q * TPF;      // j in [0, N/2)
                const float2 a  = src[j];
                const float2 bb = src[j + N / 2];
                dst[j]         = cadd(a, bb);
                dst[j + N / 2] = csub(a, bb);
            }
            cur ^= 1;
            __syncthreads();
        }

        // unpack rfft from half-size complex FFT, power, store bf16 (truncated)
        {
            const float2* Z = sh.buf[cur][sub];
            for (int k = ulane; k < K; k += TPF) {
                const float2 Zk = Z[k & (N - 1)];          // k==N wraps to Z[0]
                const float2 Zn = Z[(N - k) & (N - 1)];
                const float Er = 0.5f * (Zk.x + Zn.x);
                const float Ei = 0.5f * (Zk.y - Zn.y);
                const float Dr = Zk.x - Zn.x;
                const float Di = Zk.y + Zn.y;
                const float Or = 0.5f * Di;                 // O = -i/2 * (Zk - conj(Zn))
                const float Oi = -0.5f * Dr;
                float sw, cw;
                __sincosf(3.14159265358979f * (float)k / (float)N, &sw, &cw);
                const float Xr = Er + cw * Or + sw * Oi;
                const float Xi = Ei + cw * Oi - sw * Or;
                const float p = Xr * Xr + Xi * Xi;
                pows[k * FPB + fi + sub] = (unsigned short)(__float_as_uint(p) >> 16);
            }
        }
        // loop-top barrier protects buffers before next group's load
    }
    __syncthreads();   // pows complete; buf free for res

    // ---- mel: out[fi][m] = sum_k pow[k][fi] * mel[k][m] ----
    float* res = sh.res;
    for (int i = tid; i < FPB * NMEL; i += NT) res[i] = 0.0f;
    __syncthreads();

    constexpr int NCH = 25;                    // k-chunks
    constexpr int CH  = (K + NCH - 1) / NCH;
    if (tid < NCH * 20) {
        const int g  = tid % 20;               // m-group: mel bins 4g..4g+3
        const int c  = tid / 20;               // k-chunk
        const int k0 = c * CH;
        const int k1 = (k0 + CH < K) ? (k0 + CH) : K;
        float acc[FPB][4];
        #pragma unroll
        for (int f2 = 0; f2 < FPB; ++f2) {
            acc[f2][0] = 0.f; acc[f2][1] = 0.f; acc[f2][2] = 0.f; acc[f2][3] = 0.f;
        }
        for (int k = k0; k < k1; ++k) {
            const float4 mr = *(const float4*)(mel + (size_t)k * NMEL + 4 * g);
            const uint4* prow = (const uint4*)(pows + k * FPB);
#define ACC2(W32, BASE) { \
            const float p0 = __uint_as_float((W32) << 16); \
            const float p1 = __uint_as_float((W32) & 0xFFFF0000u); \
            acc[BASE][0] += p0 * mr.x; acc[BASE][1] += p0 * mr.y; \
            acc[BASE][2] += p0 * mr.z; acc[BASE][3] += p0 * mr.w; \
            acc[(BASE)+1][0] += p1 * mr.x; acc[(BASE)+1][1] += p1 * mr.y; \
            acc[(BASE)+1][2] += p1 * mr.z; acc[(BASE)+1][3] += p1 * mr.w; }
            {
                const uint4 pv = prow[0];
                ACC2(pv.x, 0) ACC2(pv.y, 2) ACC2(pv.z, 4) ACC2(pv.w, 6)
            }
            if constexpr (FPB == 16) {
                const uint4 pv = prow[1];
                ACC2(pv.x, 8) ACC2(pv.y, 10) ACC2(pv.z, 12) ACC2(pv.w, 14)
            }
#undef ACC2
        }
        #pragma unroll
        for (int f2 = 0; f2 < FPB; ++f2) {
            #pragma unroll
            for (int mi = 0; mi < 4; ++mi) {
                atomicAdd(&res[f2 * NMEL + 4 * g + mi], acc[f2][mi]);
            }
        }
    }
    __syncthreads();

    const size_t outbase = (size_t)b * (size_t)n0 * NMEL * 3;
    for (int i = tid; i < FPB * NMEL; i += NT) {
        const int f2 = i / NMEL;
        const int m  = i % NMEL;
        const int t  = t0 + f2;
        if (t < n0) {
            out[outbase + ((size_t)t * NMEL + m) * 3 + SZI] = logf(res[i] + 1e-16f);
        }
    }
}

extern "C" void kernel_launch(void* const* d_in, const int* in_sizes, int n_in,
                              void* d_out, int out_size, void* d_ws, size_t ws_size,
                              hipStream_t stream) {
    const float* x  = (const float*)d_in[0];
    const float* w1 = (const float*)d_in[1];
    const float* m1 = (const float*)d_in[2];
    const float* w2 = (const float*)d_in[3];
    const float* m2 = (const float*)d_in[4];
    const float* w4 = (const float*)d_in[5];
    const float* m4 = (const float*)d_in[6];
    float* out = (float*)d_out;

    const int B  = 8;
    const int T  = in_sizes[0] / B;
    const int n0 = (T + 512 + 440) / 441;   // ceil((T + 1024/2) / 441)

    spect_kernel<1024, 16, 0><<<dim3((n0 + 15) / 16, B), 512, 0, stream>>>(x, w1, m1, out, T, n0);
    spect_kernel<2048, 16, 1><<<dim3((n0 + 15) / 16, B), 512, 0, stream>>>(x, w2, m2, out, T, n0);
    spect_kernel<4096,  8, 2><<<dim3((n0 +  7) /  8, B), 512, 0, stream>>>(x, w4, m4, out, T, n0);
}